// Round 1
// baseline (361.515 us; speedup 1.0000x reference)
//
#include <hip/hip_runtime.h>
#include <math.h>

// A: (8,16,64,64,64) fp32; U: (8,16,2,64,64,64) fp32
// out: (8,80,64,64) fp32 = [A_last, A_fast, A_slow, A_deriv, E_temp] on ch axis.
//
// v2: EMA restructured as 4 independent 16-step chunk recurrences per thread
// (linear recurrence => exact chunk combine with alpha^16 factors). This
// bounds unrolling (no 64-deep load hoist -> no VGPR spill), gives 4
// independent load streams for latency hiding, and keeps the serial FMA
// chain to 16 steps x 4 ILP.
// Traffic floor: A 134 MB + U slices 8.4 MB + out 10.5 MB ~= 153 MB -> ~25 us.

#define T_DIM 64
#define HW    4096

typedef __attribute__((ext_vector_type(4))) float f4v;

__device__ __forceinline__ f4v ntload4(const float* p) {
    return __builtin_nontemporal_load((const f4v*)p);
}
__device__ __forceinline__ void ntstore4(float* p, f4v v) {
    __builtin_nontemporal_store(v, (f4v*)p);
}

__global__ __launch_bounds__(256, 2) void temporal_summarizer_kernel(
        const float* __restrict__ A, const float* __restrict__ U,
        float* __restrict__ out) {
    constexpr float AF = 0.74f, AS = 0.95f;
    constexpr float OMF = 1.0f - AF, OMS = 1.0f - AS;
    constexpr float EPS = 1e-6f;
    // chunk-combine factors alpha^16 (compile-time)
    constexpr float AF2 = AF * AF, AF4 = AF2 * AF2, AF8 = AF4 * AF4, AF16 = AF8 * AF8;
    constexpr float AS2 = AS * AS, AS4 = AS2 * AS2, AS8 = AS4 * AS4, AS16 = AS8 * AS8;

    const int blk   = blockIdx.x;
    const int split = blk & 3;              // plane quarter
    const int bm    = blk >> 2;             // 0..127
    const int m     = bm & 15;
    const int b     = bm >> 4;

    const int pix = split * (HW / 4) + threadIdx.x * 4;

    const float* pA = A + (size_t)bm * (T_DIM * HW) + pix;

    // 4 independent chunk accumulators (t-chunks of 16)
    f4v f0 = 0.f, f1 = 0.f, f2 = 0.f, f3 = 0.f;
    f4v s0 = 0.f, s1 = 0.f, s2 = 0.f, s3 = 0.f;
    f4v a62 = 0.f, a63 = 0.f;               // shift register on chunk-3 stream

    #pragma unroll 4
    for (int j = 0; j < 16; ++j) {
        f4v x0 = ntload4(pA + (size_t)(j     ) * HW);
        f4v x1 = ntload4(pA + (size_t)(j + 16) * HW);
        f4v x2 = ntload4(pA + (size_t)(j + 32) * HW);
        f4v x3 = ntload4(pA + (size_t)(j + 48) * HW);
        f0 = AF * f0 + OMF * x0;  s0 = AS * s0 + OMS * x0;
        f1 = AF * f1 + OMF * x1;  s1 = AS * s1 + OMS * x1;
        f2 = AF * f2 + OMF * x2;  s2 = AS * s2 + OMS * x2;
        f3 = AF * f3 + OMF * x3;  s3 = AS * s3 + OMS * x3;
        a62 = a63;                // after loop: a62 = x3@j=14 (t=62)
        a63 = x3;                 //             a63 = x3@j=15 (t=63)
    }

    // combine: weight for chunk c is alpha^(16*(3-c)); identical to the
    // reference weights (1-a)*a^(63-t).
    f4v fast = ((f0 * AF16 + f1) * AF16 + f2) * AF16 + f3;
    f4v slow = ((s0 * AS16 + s1) * AS16 + s2) * AS16 + s3;

    // U slices: c=0/1 at t=61 and t=63
    const float* pU = U + (size_t)bm * (2 * T_DIM * HW) + pix;
    f4v u0l = ntload4(pU + 63 * HW);
    f4v u0m = ntload4(pU + 61 * HW);
    f4v u1l = ntload4(pU + (size_t)T_DIM * HW + 63 * HW);
    f4v u1m = ntload4(pU + (size_t)T_DIM * HW + 61 * HW);

    f4v et;
    #pragma unroll
    for (int i = 0; i < 4; ++i) {
        float pq0 = 0.5f * (u0l[i] - u0m[i]);
        float er  = sqrtf(fmaxf(u0l[i] * u0l[i] + pq0 * pq0, EPS));
        float pq1 = 0.5f * (u1l[i] - u1m[i]);
        float ei  = sqrtf(fmaxf(u1l[i] * u1l[i] + pq1 * pq1, EPS));
        et[i] = sqrtf(fmaxf(er * er + ei * ei, EPS));
    }

    f4v deriv = a63 - a62;

    float* ob = out + ((size_t)(b * 80 + m)) * HW + pix;
    ntstore4(ob + 0 * 16 * HW, a63);    // A_last  (ch 0..15)
    ntstore4(ob + 1 * 16 * HW, fast);   // A_fast  (ch 16..31)
    ntstore4(ob + 2 * 16 * HW, slow);   // A_slow  (ch 32..47)
    ntstore4(ob + 3 * 16 * HW, deriv);  // A_deriv (ch 48..63)
    ntstore4(ob + 4 * 16 * HW, et);     // E_temp  (ch 64..79)
}

extern "C" void kernel_launch(void* const* d_in, const int* in_sizes, int n_in,
                              void* d_out, int out_size, void* d_ws, size_t ws_size,
                              hipStream_t stream) {
    const float* A = (const float*)d_in[0];
    const float* U = (const float*)d_in[1];
    float* out = (float*)d_out;
    dim3 grid(8 * 16 * 4);   // 512 blocks: (bm, quarter-plane)
    dim3 block(256);
    temporal_summarizer_kernel<<<grid, block, 0, stream>>>(A, U, out);
}